// Round 4
// baseline (542.592 us; speedup 1.0000x reference)
//
#include <hip/hip_runtime.h>
#include <math.h>

// Problem constants (VQ2): B=16384, D_IN=512, H=64, C=256, K=2048
#define NB 16384
#define NDIN 512
#define NH 64
#define NC 256
#define NK 2048

typedef __bf16 bf16;
typedef __bf16 bf16x4 __attribute__((ext_vector_type(4)));
typedef __bf16 bf16x8 __attribute__((ext_vector_type(8)));
typedef float f32x4 __attribute__((ext_vector_type(4)));

__device__ __forceinline__ void gload_lds16(const bf16* g, bf16* l) {
  __builtin_amdgcn_global_load_lds(
      (const __attribute__((address_space(1))) void*)g,
      (__attribute__((address_space(3))) void*)l, 16, 0, 0);
}

__device__ __forceinline__ float bfhi(unsigned u) { return __uint_as_float(u & 0xffff0000u); }
__device__ __forceinline__ float bflo(unsigned u) { return __uint_as_float(u << 16); }

// ---------------------------------------------------------------------------
// All four weight transpose+casts in one kernel.  Wt[n][k] = (bf16)W[k][n].
// ---------------------------------------------------------------------------
__global__ __launch_bounds__(256) void weight_prep(
    const float* __restrict__ We, const float* __restrict__ W0,
    const float* __restrict__ W1, const float* __restrict__ Wmu,
    bf16* __restrict__ weT, bf16* __restrict__ w0T,
    bf16* __restrict__ w1T, bf16* __restrict__ wmuT) {
  int i = blockIdx.x * 256 + threadIdx.x;
  if (i < NH * NDIN) {  // weT [64][512] from We[512][64]
    int n = i >> 9, k = i & 511;
    weT[i] = (bf16)We[k * NH + n];
    return;
  }
  i -= NH * NDIN;
  if (i < NH * NH) {  // w0T [64][64]
    int n = i >> 6, k = i & 63;
    w0T[i] = (bf16)W0[k * NH + n];
    return;
  }
  i -= NH * NH;
  if (i < NC * NH) {  // w1T [256][64] from W1[64][256]
    int n = i >> 6, k = i & 63;
    w1T[i] = (bf16)W1[k * NC + n];
    return;
  }
  i -= NC * NH;
  if (i < NC * NC) {  // wmuT [256][256]
    int n = i >> 8, k = i & 255;
    wmuT[i] = (bf16)Wmu[k * NC + n];
  }
}

// ---------------------------------------------------------------------------
// protos fp32 [NK][NC] -> bf16 + pn (norm of ROUNDED values); one wave/row
// ---------------------------------------------------------------------------
__global__ __launch_bounds__(256) void cast_protos(const float* __restrict__ P,
                                                   bf16* __restrict__ Pb,
                                                   float* __restrict__ pn) {
  int wave = (int)((blockIdx.x * 256 + threadIdx.x) >> 6);
  int lane = threadIdx.x & 63;
  if (wave >= NK) return;
  float4 v = ((const float4*)(P + (size_t)wave * NC))[lane];
  bf16x4 o;
  o[0] = (bf16)v.x; o[1] = (bf16)v.y; o[2] = (bf16)v.z; o[3] = (bf16)v.w;
  ((bf16x4*)(Pb + (size_t)wave * NC))[lane] = o;
  float s = 0.f;
#pragma unroll
  for (int j = 0; j < 4; ++j) {
    float f = (float)o[j];
    s = fmaf(f, f, s);
  }
  for (int off = 32; off > 0; off >>= 1) s += __shfl_xor(s, off);
  if (lane == 0) pn[wave] = s;
}

// ---------------------------------------------------------------------------
// MLP layers 0+1 fused: h1 = relu((x @ We + b_emb) @ W0 + b0)
//   x fp32 read directly (cast fused).  64 rows/block, wave = 16 rows.
//   h0 lives in wave-private LDS rows -> no barrier between layers.
// ---------------------------------------------------------------------------
__global__ __launch_bounds__(256) void mlp01(
    const float* __restrict__ x, const bf16* __restrict__ weT,
    const bf16* __restrict__ w0T, const float* __restrict__ b_emb,
    const float* __restrict__ b0, bf16* __restrict__ h1) {
  __shared__ __align__(16) bf16 Ws[64 * 40];   // We k-chunk [64 n][32+8]
  __shared__ __align__(16) bf16 W0s[64 * 72];  // [64 n][64+8]
  __shared__ __align__(16) bf16 H0[64 * 72];   // [64 rows][64+8]
  const int t = threadIdx.x, w = t >> 6, lane = t & 63;
  const int lm = lane & 15, kq = lane >> 4;
  const int bm = blockIdx.x * 64;
  // load W0s once (4096 elems = 512 x 16B chunks)
#pragma unroll
  for (int i = 0; i < 2; ++i) {
    int c = i * 256 + t;
    int n = c >> 3, sg = c & 7;
    *(uint4*)&W0s[n * 72 + sg * 8] = *(const uint4*)&w0T[n * NH + sg * 8];
  }
  f32x4 acc[4] = {};
  const float* xrow = x + (size_t)(bm + w * 16 + lm) * NDIN;
  for (int kc = 0; kc < 16; ++kc) {
    __syncthreads();
    {
      int n = t >> 2, sg = t & 3;  // 64 rows x 4 chunks
      *(uint4*)&Ws[n * 40 + sg * 8] = *(const uint4*)&weT[n * NDIN + kc * 32 + sg * 8];
    }
    __syncthreads();
    float4 xa = *(const float4*)&xrow[kc * 32 + kq * 8];
    float4 xc = *(const float4*)&xrow[kc * 32 + kq * 8 + 4];
    bf16x8 afr;
    afr[0] = (bf16)xa.x; afr[1] = (bf16)xa.y; afr[2] = (bf16)xa.z; afr[3] = (bf16)xa.w;
    afr[4] = (bf16)xc.x; afr[5] = (bf16)xc.y; afr[6] = (bf16)xc.z; afr[7] = (bf16)xc.w;
#pragma unroll
    for (int ni = 0; ni < 4; ++ni) {
      bf16x8 bfr = *(const bf16x8*)&Ws[(ni * 16 + lm) * 40 + kq * 8];
      acc[ni] = __builtin_amdgcn_mfma_f32_16x16x32_bf16(afr, bfr, acc[ni], 0, 0, 0);
    }
  }
  // layer0 epilogue -> H0 (wave-private rows, no barrier needed)
#pragma unroll
  for (int ni = 0; ni < 4; ++ni) {
    const float bv = b_emb[ni * 16 + lm];
#pragma unroll
    for (int rg = 0; rg < 4; ++rg)
      H0[(w * 16 + kq * 4 + rg) * 72 + ni * 16 + lm] = (bf16)(acc[ni][rg] + bv);
  }
  // layer1 (K=64)
  f32x4 a1[4] = {};
#pragma unroll
  for (int kc = 0; kc < 2; ++kc) {
    bf16x8 afr = *(const bf16x8*)&H0[(w * 16 + lm) * 72 + kc * 32 + kq * 8];
#pragma unroll
    for (int ni = 0; ni < 4; ++ni) {
      bf16x8 bfr = *(const bf16x8*)&W0s[(ni * 16 + lm) * 72 + kc * 32 + kq * 8];
      a1[ni] = __builtin_amdgcn_mfma_f32_16x16x32_bf16(afr, bfr, a1[ni], 0, 0, 0);
    }
  }
#pragma unroll
  for (int ni = 0; ni < 4; ++ni) {
    const float bv = b0[ni * 16 + lm];
#pragma unroll
    for (int rg = 0; rg < 4; ++rg)
      h1[(size_t)(bm + w * 16 + kq * 4 + rg) * NH + ni * 16 + lm] =
          (bf16)fmaxf(a1[ni][rg] + bv, 0.f);
  }
}

// ---------------------------------------------------------------------------
// Skinny GEMM, N=256: out = act(A @ Wt^T + bias).  A [NB][K] bf16, Wt [256][K].
// 64 rows/block; wave = 16 rows x 256 cols (acc 64 VGPR); weights staged in
// 20 KB LDS k-chunks; A fragments read directly from global.
// ---------------------------------------------------------------------------
template <int K, int RELU>
__global__ __launch_bounds__(256) void skinny_n256(const bf16* __restrict__ A,
                                                   const bf16* __restrict__ Wt,
                                                   const float* __restrict__ bias,
                                                   bf16* __restrict__ out) {
  __shared__ __align__(16) bf16 Ws[256 * 40];  // [256 n][32+8 k]
  const int t = threadIdx.x, w = t >> 6, lane = t & 63;
  const int lm = lane & 15, kq = lane >> 4;
  const int bm = blockIdx.x * 64;
  f32x4 acc[16] = {};
  const bf16* arow = A + (size_t)(bm + w * 16 + lm) * K;
  for (int kc = 0; kc < K / 32; ++kc) {
    __syncthreads();
#pragma unroll
    for (int i = 0; i < 4; ++i) {
      int c = i * 256 + t;
      int n = c >> 2, sg = c & 3;
      *(uint4*)&Ws[n * 40 + sg * 8] = *(const uint4*)&Wt[(size_t)n * K + kc * 32 + sg * 8];
    }
    __syncthreads();
    bf16x8 afr = *(const bf16x8*)&arow[kc * 32 + kq * 8];
#pragma unroll
    for (int ni = 0; ni < 16; ++ni) {
      bf16x8 bfr = *(const bf16x8*)&Ws[(ni * 16 + lm) * 40 + kq * 8];
      acc[ni] = __builtin_amdgcn_mfma_f32_16x16x32_bf16(afr, bfr, acc[ni], 0, 0, 0);
    }
  }
#pragma unroll
  for (int ni = 0; ni < 16; ++ni) {
    const int col = ni * 16 + lm;
    const float bv = bias[col];
#pragma unroll
    for (int rg = 0; rg < 4; ++rg) {
      float v = acc[ni][rg] + bv;
      if (RELU) v = fmaxf(v, 0.f);
      out[(size_t)(bm + w * 16 + kq * 4 + rg) * NC + col] = (bf16)v;
    }
  }
}

// ---------------------------------------------------------------------------
// Row squared-norms of bf16 [rows][NC]; one wave per row.
// ---------------------------------------------------------------------------
__global__ __launch_bounds__(256) void rownorm_bf(const bf16* __restrict__ X,
                                                  float* __restrict__ out, int rows) {
  int wave = (int)((blockIdx.x * 256 + threadIdx.x) >> 6);
  int lane = threadIdx.x & 63;
  if (wave >= rows) return;
  bf16x4 v = ((const bf16x4*)(X + (size_t)wave * NC))[lane];
  float s = 0.f;
#pragma unroll
  for (int j = 0; j < 4; ++j) {
    float f = (float)v[j];
    s = fmaf(f, f, s);
  }
  for (int off = 32; off > 0; off >>= 1) s += __shfl_xor(s, off);
  if (lane == 0) out[wave] = s;
}

// ---------------------------------------------------------------------------
// Column sums of mub [NB][NC] (bf16) -> colsum [NC] fp32
// ---------------------------------------------------------------------------
__global__ __launch_bounds__(256) void colsum_mu(const bf16* __restrict__ mub,
                                                 float* __restrict__ colsum) {
  const int c = threadIdx.x;
  const int r0 = blockIdx.x * 64;
  float acc = 0.f;
  for (int r = 0; r < 64; ++r) acc += (float)mub[(size_t)(r0 + r) * NC + c];
  atomicAdd(&colsum[c], acc);
}

// ---------------------------------------------------------------------------
// S-GEMM (MFMA, swizzled LDS): S_bf16 = 2*mu·p - rn - pn, argmax(s+gumbel)
// fused via coalesced LDS-transposed epilogue + packed u64 atomicMax.
// ---------------------------------------------------------------------------
__global__ __launch_bounds__(256) void gemm_S_mfma(
    const bf16* __restrict__ A, const bf16* __restrict__ Bt,
    const float* __restrict__ rn, const float* __restrict__ pn,
    const float* __restrict__ gum, bf16* __restrict__ S,
    unsigned long long* __restrict__ packed) {
  __shared__ __align__(16) unsigned char smem[4 * 16 * 68 * 4];  // 17408 B
  bf16* As = (bf16*)smem;            // 8 KB (k-loop)
  bf16* Bs = (bf16*)(smem + 8192);   // 8 KB (k-loop)
  const int t = threadIdx.x;
  const int w = t >> 6, lane = t & 63;
  const int bm = blockIdx.x * 128, bn = blockIdx.y * 128;
  const int wm = (w >> 1) * 64, wn = (w & 1) * 64;
  const int lm = lane & 15, kq = lane >> 4;
  const int xorc = (lm & 3) ^ ((lm >> 2) & 3);
  const int pc8 = (kq ^ xorc) << 3;
  f32x4 acc[4][4] = {};
  for (int k0 = 0; k0 < NC; k0 += 32) {
    __syncthreads();
#pragma unroll
    for (int i = 0; i < 2; ++i) {
      int c = i * 256 + t;
      int r = c >> 2, sg = c & 3;
      int kc = sg ^ (r & 3) ^ ((r >> 2) & 3);
      gload_lds16(&A[(size_t)(bm + r) * NC + k0 + kc * 8], &As[c * 8]);
      gload_lds16(&Bt[(size_t)(bn + r) * NC + k0 + kc * 8], &Bs[c * 8]);
    }
    __syncthreads();
    bf16x8 a[4], b[4];
#pragma unroll
    for (int i = 0; i < 4; ++i) {
      a[i] = *(const bf16x8*)&As[(wm + i * 16 + lm) * 32 + pc8];
      b[i] = *(const bf16x8*)&Bs[(wn + i * 16 + lm) * 32 + pc8];
    }
#pragma unroll
    for (int mi = 0; mi < 4; ++mi)
#pragma unroll
      for (int ni = 0; ni < 4; ++ni)
        acc[mi][ni] = __builtin_amdgcn_mfma_f32_16x16x32_bf16(a[mi], b[ni], acc[mi][ni], 0, 0, 0);
  }
  __syncthreads();  // staging reads done; reuse smem as per-wave fp32 slabs
  float* ws = (float*)smem + w * (16 * 68);
  const int colw = bn + wn + lane;  // this wave's 64 columns
  const float pnv = pn[colw];
#pragma unroll
  for (int mi = 0; mi < 4; ++mi) {
#pragma unroll
    for (int ni = 0; ni < 4; ++ni)
#pragma unroll
      for (int rg = 0; rg < 4; ++rg)
        ws[(kq * 4 + rg) * 68 + ni * 16 + lm] = acc[mi][ni][rg];
    // wave-private slab; wave lockstep -> no barrier
    const int rowbase = bm + wm + mi * 16;
#pragma unroll
    for (int rr = 0; rr < 16; ++rr) {
      const int row = rowbase + rr;
      float sv = 2.f * ws[rr * 68 + lane] - rn[row] - pnv;
      S[(size_t)row * NK + colw] = (bf16)sv;
      float v = sv + gum[(size_t)row * NK + colw];
      float m = v;
      for (int off = 32; off > 0; off >>= 1) m = fmaxf(m, __shfl_xor(m, off));
      unsigned long long mask = __ballot(v == m);
      int sel = __ffsll((unsigned long long)mask) - 1;  // smallest lane = smallest col
      if (lane == sel) {
        unsigned kb = __float_as_uint(v);
        kb = (kb & 0x80000000u) ? ~kb : (kb | 0x80000000u);
        unsigned long long pk =
            ((unsigned long long)kb << 32) | (unsigned)(~(unsigned)colw);
        atomicMax(&packed[row], pk);
      }
    }
  }
}

// ---------------------------------------------------------------------------
// Row pass: softmax stats over bf16 S + proto gather via packed argmax.
// ---------------------------------------------------------------------------
__global__ __launch_bounds__(256) void row_pass(
    const bf16* __restrict__ S, const unsigned long long* __restrict__ packed,
    const float* __restrict__ protos, float* __restrict__ out,
    float* __restrict__ csp, float* __restrict__ ml) {
  __shared__ float seg[4][NK];
  const int t = threadIdx.x, w = t >> 6, lane = t & 63;
  for (int k = lane; k < NK; k += 64) seg[w][k] = 0.f;
  for (int rr = 0; rr < 4; ++rr) {
    const int b = blockIdx.x * 16 + w * 4 + rr;
    const bf16* Srow = S + (size_t)b * NK;
    float s[32];
#pragma unroll
    for (int j = 0; j < 16; ++j) {
      unsigned u = *(const unsigned*)&Srow[j * 128 + lane * 2];
      s[2 * j] = bflo(u);
      s[2 * j + 1] = bfhi(u);
    }
    float m = -INFINITY;
#pragma unroll
    for (int j = 0; j < 32; ++j) m = fmaxf(m, s[j]);
    for (int off = 32; off > 0; off >>= 1) m = fmaxf(m, __shfl_xor(m, off));
    float Z = 0.f;
#pragma unroll
    for (int j = 0; j < 32; ++j) Z += expf(s[j] - m);
    for (int off = 32; off > 0; off >>= 1) Z += __shfl_xor(Z, off);
    const float mls = m + logf(Z);
    if (lane == 0) ml[b] = mls;
#pragma unroll
    for (int j = 0; j < 16; ++j) {
      float2* p = (float2*)&seg[w][j * 128 + lane * 2];
      float2 cur = *p;
      cur.x += expf(s[2 * j] - mls);
      cur.y += expf(s[2 * j + 1] - mls);
      *p = cur;
    }
    const unsigned col = ~(unsigned)(packed[b] & 0xffffffffull);
    ((float4*)(out + (size_t)b * NC))[lane] =
        ((const float4*)(protos + (size_t)col * NC))[lane];
  }
  __syncthreads();
  for (int k = t; k < NK; k += 256)
    atomicAdd(&csp[k], seg[0][k] + seg[1][k] + seg[2][k] + seg[3][k]);
}

// ---------------------------------------------------------------------------
// Finalize: closed-form csl + loss.
// ---------------------------------------------------------------------------
__global__ __launch_bounds__(256) void finalize_v2(
    const float* __restrict__ csp, const float* __restrict__ colsum,
    const bf16* __restrict__ pb, const float* __restrict__ pn,
    const float* __restrict__ rn, const float* __restrict__ ml,
    float* __restrict__ out_loss) {
  const int t = threadIdx.x;
  __shared__ double sd[256];
  __shared__ float cs[256];
  double rs = 0.0, ms = 0.0;
  for (int i = t; i < NB; i += 256) {
    rs += (double)rn[i];
    ms += (double)ml[i];
  }
  cs[t] = colsum[t];
  sd[t] = rs;
  __syncthreads();
  for (int off = 128; off > 0; off >>= 1) {
    if (t < off) sd[t] += sd[t + off];
    __syncthreads();
  }
  const double rnsum = sd[0];
  __syncthreads();
  sd[t] = ms;
  __syncthreads();
  for (int off = 128; off > 0; off >>= 1) {
    if (t < off) sd[t] += sd[t + off];
    __syncthreads();
  }
  const double mlsum = sd[0];
  __syncthreads();
  double cap = 0.0, plp = 0.0;
  for (int k = t; k < NK; k += 256) {
    const bf16* pr = pb + (size_t)k * NC;
    float dot = 0.f;
    for (int c = 0; c < NC; c += 8) {
      bf16x8 v = *(const bf16x8*)&pr[c];
#pragma unroll
      for (int e = 0; e < 8; ++e) dot = fmaf(cs[c + e], (float)v[e], dot);
    }
    double csl = 2.0 * (double)dot - rnsum - (double)NB * (double)pn[k] - mlsum;
    double mlp = csl * (1.0 / (double)NB);
    double prior = (double)csp[k] * (1.0 / (double)NB) + 1e-6;
    double lp = log(prior);
    cap += prior * (lp - mlp);
    plp += prior * lp;
  }
  sd[t] = cap;
  __syncthreads();
  for (int off = 128; off > 0; off >>= 1) {
    if (t < off) sd[t] += sd[t + off];
    __syncthreads();
  }
  const double capT = sd[0];
  __syncthreads();
  sd[t] = plp;
  __syncthreads();
  for (int off = 128; off > 0; off >>= 1) {
    if (t < off) sd[t] += sd[t + off];
    __syncthreads();
  }
  if (t == 0) out_loss[0] = (float)(0.01 * capT + 0.001 * sd[0]);
}

// ---------------------------------------------------------------------------
extern "C" void kernel_launch(void* const* d_in, const int* in_sizes, int n_in,
                              void* d_out, int out_size, void* d_ws, size_t ws_size,
                              hipStream_t stream) {
  const float* x = (const float*)d_in[0];
  const float* gumbel = (const float*)d_in[1];
  const float* W_emb = (const float*)d_in[2];
  const float* b_emb = (const float*)d_in[3];
  const float* W0 = (const float*)d_in[4];
  const float* b0 = (const float*)d_in[5];
  const float* W1 = (const float*)d_in[6];
  const float* b1 = (const float*)d_in[7];
  const float* W_mu = (const float*)d_in[8];
  const float* b_mu = (const float*)d_in[9];
  // d_in[10]=W_var, d_in[11]=b_var unused (logvar dead downstream)
  const float* protos = (const float*)d_in[12];
  float* out = (float*)d_out;

  // workspace layout
  bf16* Sb16 = (bf16*)d_ws;                                   // [NB][NK] bf16
  float* rn = (float*)(Sb16 + (size_t)NB * NK);               // [NB]
  float* pn = rn + NB;                                        // [NK]
  float* ml = pn + NK;                                        // [NB]
  float* csp = ml + NB;                                       // [NK]  (zeroed)
  float* colsum = csp + NK;                                   // [NC]  (zeroed)
  unsigned long long* packed = (unsigned long long*)(colsum + NC);  // [NB] (zeroed)
  bf16* h1 = (bf16*)(packed + NB);                            // [NB][NH]
  bf16* h2 = h1 + (size_t)NB * NH;                            // [NB][NC]
  bf16* mub = h2 + (size_t)NB * NC;                           // [NB][NC]
  bf16* pb = mub + (size_t)NB * NC;                           // [NK][NC]
  bf16* weT = pb + (size_t)NK * NC;                           // [NH][NDIN]
  bf16* w0T = weT + NH * NDIN;                                // [NH][NH]
  bf16* w1T = w0T + NH * NH;                                  // [NC][NH]
  bf16* wmuT = w1T + NC * NH;                                 // [NC][NC]

  hipMemsetAsync(csp, 0, (NK + NC) * sizeof(float) + NB * sizeof(unsigned long long), stream);

  dim3 blk(256);
  const int wp_elems = NH * NDIN + NH * NH + NC * NH + NC * NC;
  weight_prep<<<(wp_elems + 255) / 256, blk, 0, stream>>>(W_emb, W0, W1, W_mu,
                                                          weT, w0T, w1T, wmuT);
  cast_protos<<<NK / 4, blk, 0, stream>>>(protos, pb, pn);

  mlp01<<<NB / 64, blk, 0, stream>>>(x, weT, w0T, b_emb, b0, h1);
  skinny_n256<NH, 1><<<NB / 64, blk, 0, stream>>>(h1, w1T, b1, h2);
  skinny_n256<NC, 0><<<NB / 64, blk, 0, stream>>>(h2, wmuT, b_mu, mub);

  rownorm_bf<<<NB / 4, blk, 0, stream>>>(mub, rn, NB);
  colsum_mu<<<NB / 64, blk, 0, stream>>>(mub, colsum);

  gemm_S_mfma<<<dim3(NB / 128, NK / 128), blk, 0, stream>>>(mub, pb, rn, pn,
                                                            gumbel, Sb16, packed);
  row_pass<<<NB / 16, blk, 0, stream>>>(Sb16, packed, protos, out, csp, ml);
  finalize_v2<<<1, blk, 0, stream>>>(csp, colsum, pb, pn, rn, ml,
                                     out + (size_t)NB * NC);
}

// Round 5
// 429.462 us; speedup vs baseline: 1.2634x; 1.2634x over previous
//
#include <hip/hip_runtime.h>
#include <math.h>

// Problem constants (VQ2): B=16384, D_IN=512, H=64, C=256, K=2048
#define NB 16384
#define NDIN 512
#define NH 64
#define NC 256
#define NK 2048

typedef __bf16 bf16;
typedef __bf16 bf16x4 __attribute__((ext_vector_type(4)));
typedef __bf16 bf16x8 __attribute__((ext_vector_type(8)));
typedef float f32x4 __attribute__((ext_vector_type(4)));

__device__ __forceinline__ void gload_lds16(const bf16* g, bf16* l) {
  __builtin_amdgcn_global_load_lds(
      (const __attribute__((address_space(1))) void*)g,
      (__attribute__((address_space(3))) void*)l, 16, 0, 0);
}

__device__ __forceinline__ float bfhi(unsigned u) { return __uint_as_float(u & 0xffff0000u); }
__device__ __forceinline__ float bflo(unsigned u) { return __uint_as_float(u << 16); }

// ---------------------------------------------------------------------------
// All four weight transpose+casts in one kernel.  Wt[n][k] = (bf16)W[k][n].
// ---------------------------------------------------------------------------
__global__ __launch_bounds__(256) void weight_prep(
    const float* __restrict__ We, const float* __restrict__ W0,
    const float* __restrict__ W1, const float* __restrict__ Wmu,
    bf16* __restrict__ weT, bf16* __restrict__ w0T,
    bf16* __restrict__ w1T, bf16* __restrict__ wmuT) {
  int i = blockIdx.x * 256 + threadIdx.x;
  if (i < NH * NDIN) {  // weT [64][512] from We[512][64]
    int n = i >> 9, k = i & 511;
    weT[i] = (bf16)We[k * NH + n];
    return;
  }
  i -= NH * NDIN;
  if (i < NH * NH) {  // w0T [64][64]
    int n = i >> 6, k = i & 63;
    w0T[i] = (bf16)W0[k * NH + n];
    return;
  }
  i -= NH * NH;
  if (i < NC * NH) {  // w1T [256][64] from W1[64][256]
    int n = i >> 6, k = i & 63;
    w1T[i] = (bf16)W1[k * NC + n];
    return;
  }
  i -= NC * NH;
  if (i < NC * NC) {  // wmuT [256][256]
    int n = i >> 8, k = i & 255;
    wmuT[i] = (bf16)Wmu[k * NC + n];
  }
}

// ---------------------------------------------------------------------------
// protos fp32 [NK][NC] -> bf16 + pn (norm of ROUNDED values); one wave/row
// ---------------------------------------------------------------------------
__global__ __launch_bounds__(256) void cast_protos(const float* __restrict__ P,
                                                   bf16* __restrict__ Pb,
                                                   float* __restrict__ pn) {
  int wave = (int)((blockIdx.x * 256 + threadIdx.x) >> 6);
  int lane = threadIdx.x & 63;
  if (wave >= NK) return;
  float4 v = ((const float4*)(P + (size_t)wave * NC))[lane];
  bf16x4 o;
  o[0] = (bf16)v.x; o[1] = (bf16)v.y; o[2] = (bf16)v.z; o[3] = (bf16)v.w;
  ((bf16x4*)(Pb + (size_t)wave * NC))[lane] = o;
  float s = 0.f;
#pragma unroll
  for (int j = 0; j < 4; ++j) {
    float f = (float)o[j];
    s = fmaf(f, f, s);
  }
  for (int off = 32; off > 0; off >>= 1) s += __shfl_xor(s, off);
  if (lane == 0) pn[wave] = s;
}

// ---------------------------------------------------------------------------
// Fully fused 4-layer MLP.  Block = 16 rows, 4 waves; wave w owns the
// 16-col (N=64 layers) / 64-col (N=256 layers) column group w.
// Weights read as MFMA B-fragments directly from global (L1/L2-hot, no
// staging barriers).  x staged once to LDS (fp32 read fused with cast).
// Also emits rn[row] = ||bf16(mu_row)||^2.
// ---------------------------------------------------------------------------
__global__ __launch_bounds__(256) void fused_mlp(
    const float* __restrict__ x, const bf16* __restrict__ weT,
    const bf16* __restrict__ w0T, const bf16* __restrict__ w1T,
    const bf16* __restrict__ wmuT,
    const float* __restrict__ b_emb, const float* __restrict__ b0,
    const float* __restrict__ b1, const float* __restrict__ b_mu,
    bf16* __restrict__ mub, float* __restrict__ rn) {
  __shared__ __align__(16) bf16 Xs[16 * 520];   // x block, pad 520
  __shared__ __align__(16) bf16 H0[16 * 72];
  __shared__ __align__(16) bf16 H1[16 * 72];
  __shared__ __align__(16) bf16 H2[16 * 264];
  __shared__ float Rr[4][16];
  const int t = threadIdx.x, w = t >> 6, lane = t & 63;
  const int lm = lane & 15, kq = lane >> 4;
  const int bm = blockIdx.x * 16;
  // stage x: 16 rows x 512 fp32 -> bf16 (coalesced float4 reads)
#pragma unroll
  for (int i = 0; i < 8; ++i) {
    int c = i * 256 + t;           // 2048 float4 chunks, 128 per row
    int row = c >> 7, off = c & 127;
    float4 v = *(const float4*)&x[(size_t)(bm + row) * NDIN + off * 4];
    bf16x4 o;
    o[0] = (bf16)v.x; o[1] = (bf16)v.y; o[2] = (bf16)v.z; o[3] = (bf16)v.w;
    *(bf16x4*)&Xs[row * 520 + off * 4] = o;
  }
  __syncthreads();
  // L0: h0 = x @ We + b_emb  (K=512, wave cols w*16+lm)
  f32x4 c0 = {};
#pragma unroll
  for (int kc = 0; kc < 16; ++kc) {
    bf16x8 a = *(const bf16x8*)&Xs[lm * 520 + kc * 32 + kq * 8];
    bf16x8 b = *(const bf16x8*)&weT[(size_t)(w * 16 + lm) * NDIN + kc * 32 + kq * 8];
    c0 = __builtin_amdgcn_mfma_f32_16x16x32_bf16(a, b, c0, 0, 0, 0);
  }
  {
    const float bv = b_emb[w * 16 + lm];
#pragma unroll
    for (int rg = 0; rg < 4; ++rg)
      H0[(kq * 4 + rg) * 72 + w * 16 + lm] = (bf16)(c0[rg] + bv);
  }
  __syncthreads();
  // L1: h1 = relu(h0 @ W0 + b0)  (K=64)
  f32x4 c1 = {};
#pragma unroll
  for (int kc = 0; kc < 2; ++kc) {
    bf16x8 a = *(const bf16x8*)&H0[lm * 72 + kc * 32 + kq * 8];
    bf16x8 b = *(const bf16x8*)&w0T[(size_t)(w * 16 + lm) * NH + kc * 32 + kq * 8];
    c1 = __builtin_amdgcn_mfma_f32_16x16x32_bf16(a, b, c1, 0, 0, 0);
  }
  {
    const float bv = b0[w * 16 + lm];
#pragma unroll
    for (int rg = 0; rg < 4; ++rg)
      H1[(kq * 4 + rg) * 72 + w * 16 + lm] = (bf16)fmaxf(c1[rg] + bv, 0.f);
  }
  __syncthreads();
  // L2: h2 = relu(h1 @ W1 + b1)  (K=64, wave cols w*64..w*64+63)
  f32x4 c2[4] = {};
#pragma unroll
  for (int kc = 0; kc < 2; ++kc) {
    bf16x8 a = *(const bf16x8*)&H1[lm * 72 + kc * 32 + kq * 8];
#pragma unroll
    for (int ni = 0; ni < 4; ++ni) {
      bf16x8 b = *(const bf16x8*)&w1T[(size_t)(w * 64 + ni * 16 + lm) * NH + kc * 32 + kq * 8];
      c2[ni] = __builtin_amdgcn_mfma_f32_16x16x32_bf16(a, b, c2[ni], 0, 0, 0);
    }
  }
#pragma unroll
  for (int ni = 0; ni < 4; ++ni) {
    const float bv = b1[w * 64 + ni * 16 + lm];
#pragma unroll
    for (int rg = 0; rg < 4; ++rg)
      H2[(kq * 4 + rg) * 264 + w * 64 + ni * 16 + lm] = (bf16)fmaxf(c2[ni][rg] + bv, 0.f);
  }
  __syncthreads();
  // L3: mu = h2 @ Wmu + b_mu  (K=256)
  f32x4 c3[4] = {};
#pragma unroll
  for (int kc = 0; kc < 8; ++kc) {
    bf16x8 a = *(const bf16x8*)&H2[lm * 264 + kc * 32 + kq * 8];
#pragma unroll
    for (int ni = 0; ni < 4; ++ni) {
      bf16x8 b = *(const bf16x8*)&wmuT[(size_t)(w * 64 + ni * 16 + lm) * NC + kc * 32 + kq * 8];
      c3[ni] = __builtin_amdgcn_mfma_f32_16x16x32_bf16(a, b, c3[ni], 0, 0, 0);
    }
  }
  // epilogue: store bf16 mu + fused row-norm of ROUNDED values
  float rpart[4] = {0.f, 0.f, 0.f, 0.f};
#pragma unroll
  for (int ni = 0; ni < 4; ++ni) {
    const int col = w * 64 + ni * 16 + lm;
    const float bv = b_mu[col];
#pragma unroll
    for (int rg = 0; rg < 4; ++rg) {
      bf16 q = (bf16)(c3[ni][rg] + bv);
      mub[(size_t)(bm + kq * 4 + rg) * NC + col] = q;
      float f = (float)q;
      rpart[rg] = fmaf(f, f, rpart[rg]);
    }
  }
#pragma unroll
  for (int off = 1; off < 16; off <<= 1)
#pragma unroll
    for (int rg = 0; rg < 4; ++rg) rpart[rg] += __shfl_xor(rpart[rg], off);
  if (lm == 0)
#pragma unroll
    for (int rg = 0; rg < 4; ++rg) Rr[w][kq * 4 + rg] = rpart[rg];
  __syncthreads();
  if (t < 16) rn[bm + t] = Rr[0][t] + Rr[1][t] + Rr[2][t] + Rr[3][t];
}

// ---------------------------------------------------------------------------
// Column sums of mub [NB][NC] (bf16) -> colsum [NC] fp32
// ---------------------------------------------------------------------------
__global__ __launch_bounds__(256) void colsum_mu(const bf16* __restrict__ mub,
                                                 float* __restrict__ colsum) {
  const int c = threadIdx.x;
  const int r0 = blockIdx.x * 64;
  float acc = 0.f;
  for (int r = 0; r < 64; ++r) acc += (float)mub[(size_t)(r0 + r) * NC + c];
  atomicAdd(&colsum[c], acc);
}

// ---------------------------------------------------------------------------
// S-GEMM (MFMA, swizzled LDS): S_bf16 = 2*mu·p - rn - pn, with fused
// argmax(s+gumbel) in native C-layout: all loads/stores independent-issue,
// 4-deep shuffle reduce over the 16 lm lanes, one atomicMax per row.
// ---------------------------------------------------------------------------
__global__ __launch_bounds__(256) void gemm_S_mfma(
    const bf16* __restrict__ A, const bf16* __restrict__ Bt,
    const float* __restrict__ rn, const float* __restrict__ pn,
    const float* __restrict__ gum, bf16* __restrict__ S,
    unsigned long long* __restrict__ packed) {
  __shared__ __align__(16) bf16 As[128 * 32];
  __shared__ __align__(16) bf16 Bs[128 * 32];
  const int t = threadIdx.x;
  const int w = t >> 6, lane = t & 63;
  const int bm = blockIdx.x * 128, bn = blockIdx.y * 128;
  const int wm = (w >> 1) * 64, wn = (w & 1) * 64;
  const int lm = lane & 15, kq = lane >> 4;
  const int xorc = (lm & 3) ^ ((lm >> 2) & 3);
  const int pc8 = (kq ^ xorc) << 3;
  f32x4 acc[4][4] = {};
  for (int k0 = 0; k0 < NC; k0 += 32) {
    __syncthreads();
#pragma unroll
    for (int i = 0; i < 2; ++i) {
      int c = i * 256 + t;
      int r = c >> 2, sg = c & 3;
      int kc = sg ^ (r & 3) ^ ((r >> 2) & 3);
      gload_lds16(&A[(size_t)(bm + r) * NC + k0 + kc * 8], &As[c * 8]);
      gload_lds16(&Bt[(size_t)(bn + r) * NC + k0 + kc * 8], &Bs[c * 8]);
    }
    __syncthreads();
    bf16x8 a[4], b[4];
#pragma unroll
    for (int i = 0; i < 4; ++i) {
      a[i] = *(const bf16x8*)&As[(wm + i * 16 + lm) * 32 + pc8];
      b[i] = *(const bf16x8*)&Bs[(wn + i * 16 + lm) * 32 + pc8];
    }
#pragma unroll
    for (int mi = 0; mi < 4; ++mi)
#pragma unroll
      for (int ni = 0; ni < 4; ++ni)
        acc[mi][ni] = __builtin_amdgcn_mfma_f32_16x16x32_bf16(a[mi], b[ni], acc[mi][ni], 0, 0, 0);
  }
  // epilogue — native C layout
  float pnv[4];
#pragma unroll
  for (int ni = 0; ni < 4; ++ni) pnv[ni] = pn[bn + wn + ni * 16 + lm];
#pragma unroll
  for (int mi = 0; mi < 4; ++mi) {
    const int row0 = bm + wm + mi * 16 + kq * 4;
    float g[4][4];
#pragma unroll
    for (int rg = 0; rg < 4; ++rg)
#pragma unroll
      for (int ni = 0; ni < 4; ++ni)
        g[rg][ni] = gum[(size_t)(row0 + rg) * NK + bn + wn + ni * 16 + lm];
    unsigned long long best[4];
#pragma unroll
    for (int rg = 0; rg < 4; ++rg) {
      const float rv = rn[row0 + rg];
      unsigned long long bb = 0ull;
#pragma unroll
      for (int ni = 0; ni < 4; ++ni) {
        const int col = bn + wn + ni * 16 + lm;
        float sv = 2.f * acc[mi][ni][rg] - rv - pnv[ni];
        S[(size_t)(row0 + rg) * NK + col] = (bf16)sv;
        float v = sv + g[rg][ni];
        unsigned kb = __float_as_uint(v);
        kb = (kb & 0x80000000u) ? ~kb : (kb | 0x80000000u);
        unsigned long long pk =
            ((unsigned long long)kb << 32) | (unsigned)(~(unsigned)col);
        if (pk > bb) bb = pk;
      }
      best[rg] = bb;
    }
#pragma unroll
    for (int off = 1; off < 16; off <<= 1) {
#pragma unroll
      for (int rg = 0; rg < 4; ++rg) {
        unsigned lo = (unsigned)best[rg], hi = (unsigned)(best[rg] >> 32);
        unsigned olo = __shfl_xor(lo, off), ohi = __shfl_xor(hi, off);
        unsigned long long o = ((unsigned long long)ohi << 32) | olo;
        if (o > best[rg]) best[rg] = o;
      }
    }
    if (lm == 0) {
#pragma unroll
      for (int rg = 0; rg < 4; ++rg) atomicMax(&packed[row0 + rg], best[rg]);
    }
  }
}

// ---------------------------------------------------------------------------
// Row pass: softmax stats over bf16 S + proto gather via packed argmax.
// ---------------------------------------------------------------------------
__global__ __launch_bounds__(256) void row_pass(
    const bf16* __restrict__ S, const unsigned long long* __restrict__ packed,
    const float* __restrict__ protos, float* __restrict__ out,
    float* __restrict__ csp, float* __restrict__ ml) {
  __shared__ float seg[4][NK];
  const int t = threadIdx.x, w = t >> 6, lane = t & 63;
  for (int k = lane; k < NK; k += 64) seg[w][k] = 0.f;
  for (int rr = 0; rr < 4; ++rr) {
    const int b = blockIdx.x * 16 + w * 4 + rr;
    const bf16* Srow = S + (size_t)b * NK;
    float s[32];
#pragma unroll
    for (int j = 0; j < 16; ++j) {
      unsigned u = *(const unsigned*)&Srow[j * 128 + lane * 2];
      s[2 * j] = bflo(u);
      s[2 * j + 1] = bfhi(u);
    }
    float m = -INFINITY;
#pragma unroll
    for (int j = 0; j < 32; ++j) m = fmaxf(m, s[j]);
    for (int off = 32; off > 0; off >>= 1) m = fmaxf(m, __shfl_xor(m, off));
    float Z = 0.f;
#pragma unroll
    for (int j = 0; j < 32; ++j) Z += expf(s[j] - m);
    for (int off = 32; off > 0; off >>= 1) Z += __shfl_xor(Z, off);
    const float mls = m + logf(Z);
    if (lane == 0) ml[b] = mls;
#pragma unroll
    for (int j = 0; j < 16; ++j) {
      float2* p = (float2*)&seg[w][j * 128 + lane * 2];
      float2 cur = *p;
      cur.x += expf(s[2 * j] - mls);
      cur.y += expf(s[2 * j + 1] - mls);
      *p = cur;
    }
    const unsigned col = ~(unsigned)(packed[b] & 0xffffffffull);
    ((float4*)(out + (size_t)b * NC))[lane] =
        ((const float4*)(protos + (size_t)col * NC))[lane];
  }
  __syncthreads();
  for (int k = t; k < NK; k += 256)
    atomicAdd(&csp[k], seg[0][k] + seg[1][k] + seg[2][k] + seg[3][k]);
}

// ---------------------------------------------------------------------------
// Finalize: closed-form csl + loss.
// ---------------------------------------------------------------------------
__global__ __launch_bounds__(256) void finalize_v2(
    const float* __restrict__ csp, const float* __restrict__ colsum,
    const bf16* __restrict__ pb, const float* __restrict__ pn,
    const float* __restrict__ rn, const float* __restrict__ ml,
    float* __restrict__ out_loss) {
  const int t = threadIdx.x;
  __shared__ double sd[256];
  __shared__ float cs[256];
  double rs = 0.0, ms = 0.0;
  for (int i = t; i < NB; i += 256) {
    rs += (double)rn[i];
    ms += (double)ml[i];
  }
  cs[t] = colsum[t];
  sd[t] = rs;
  __syncthreads();
  for (int off = 128; off > 0; off >>= 1) {
    if (t < off) sd[t] += sd[t + off];
    __syncthreads();
  }
  const double rnsum = sd[0];
  __syncthreads();
  sd[t] = ms;
  __syncthreads();
  for (int off = 128; off > 0; off >>= 1) {
    if (t < off) sd[t] += sd[t + off];
    __syncthreads();
  }
  const double mlsum = sd[0];
  __syncthreads();
  double cap = 0.0, plp = 0.0;
  for (int k = t; k < NK; k += 256) {
    const bf16* pr = pb + (size_t)k * NC;
    float dot = 0.f;
    for (int c = 0; c < NC; c += 8) {
      bf16x8 v = *(const bf16x8*)&pr[c];
#pragma unroll
      for (int e = 0; e < 8; ++e) dot = fmaf(cs[c + e], (float)v[e], dot);
    }
    double csl = 2.0 * (double)dot - rnsum - (double)NB * (double)pn[k] - mlsum;
    double mlp = csl * (1.0 / (double)NB);
    double prior = (double)csp[k] * (1.0 / (double)NB) + 1e-6;
    double lp = log(prior);
    cap += prior * (lp - mlp);
    plp += prior * lp;
  }
  sd[t] = cap;
  __syncthreads();
  for (int off = 128; off > 0; off >>= 1) {
    if (t < off) sd[t] += sd[t + off];
    __syncthreads();
  }
  const double capT = sd[0];
  __syncthreads();
  sd[t] = plp;
  __syncthreads();
  for (int off = 128; off > 0; off >>= 1) {
    if (t < off) sd[t] += sd[t + off];
    __syncthreads();
  }
  if (t == 0) out_loss[0] = (float)(0.01 * capT + 0.001 * sd[0]);
}

// ---------------------------------------------------------------------------
extern "C" void kernel_launch(void* const* d_in, const int* in_sizes, int n_in,
                              void* d_out, int out_size, void* d_ws, size_t ws_size,
                              hipStream_t stream) {
  const float* x = (const float*)d_in[0];
  const float* gumbel = (const float*)d_in[1];
  const float* W_emb = (const float*)d_in[2];
  const float* b_emb = (const float*)d_in[3];
  const float* W0 = (const float*)d_in[4];
  const float* b0 = (const float*)d_in[5];
  const float* W1 = (const float*)d_in[6];
  const float* b1 = (const float*)d_in[7];
  const float* W_mu = (const float*)d_in[8];
  const float* b_mu = (const float*)d_in[9];
  // d_in[10]=W_var, d_in[11]=b_var unused (logvar dead downstream)
  const float* protos = (const float*)d_in[12];
  float* out = (float*)d_out;

  // workspace layout
  bf16* Sb16 = (bf16*)d_ws;                                   // [NB][NK] bf16
  float* rn = (float*)(Sb16 + (size_t)NB * NK);               // [NB]
  float* pn = rn + NB;                                        // [NK]
  float* ml = pn + NK;                                        // [NB]
  float* csp = ml + NB;                                       // [NK]  (zeroed)
  float* colsum = csp + NK;                                   // [NC]  (zeroed)
  unsigned long long* packed = (unsigned long long*)(colsum + NC);  // [NB] (zeroed)
  bf16* mub = (bf16*)(packed + NB);                           // [NB][NC]
  bf16* pb = mub + (size_t)NB * NC;                           // [NK][NC]
  bf16* weT = pb + (size_t)NK * NC;                           // [NH][NDIN]
  bf16* w0T = weT + NH * NDIN;                                // [NH][NH]
  bf16* w1T = w0T + NH * NH;                                  // [NC][NH]
  bf16* wmuT = w1T + NC * NH;                                 // [NC][NC]

  hipMemsetAsync(csp, 0, (NK + NC) * sizeof(float) + NB * sizeof(unsigned long long), stream);

  dim3 blk(256);
  const int wp_elems = NH * NDIN + NH * NH + NC * NH + NC * NC;
  weight_prep<<<(wp_elems + 255) / 256, blk, 0, stream>>>(W_emb, W0, W1, W_mu,
                                                          weT, w0T, w1T, wmuT);
  cast_protos<<<NK / 4, blk, 0, stream>>>(protos, pb, pn);

  fused_mlp<<<NB / 16, blk, 0, stream>>>(x, weT, w0T, w1T, wmuT,
                                         b_emb, b0, b1, b_mu, mub, rn);
  colsum_mu<<<NB / 64, blk, 0, stream>>>(mub, colsum);

  gemm_S_mfma<<<dim3(NB / 128, NK / 128), blk, 0, stream>>>(mub, pb, rn, pn,
                                                            gumbel, Sb16, packed);
  row_pass<<<NB / 16, blk, 0, stream>>>(Sb16, packed, protos, out, csp, ml);
  finalize_v2<<<1, blk, 0, stream>>>(csp, colsum, pb, pn, rn, ml,
                                     out + (size_t)NB * NC);
}